// Round 11
// baseline (125.307 us; speedup 1.0000x reference)
//
#include <hip/hip_runtime.h>
#include <math.h>

// Problem constants
#define BATCH 32
#define H 512
#define W 512
#define OUT_HW 502          // 512 - 11 + 1
#define TS_X 32             // output strip width
#define BAND 48             // output rows per band (R11: was 64)
#define NBANDS 3
#define STRIP (BAND * NBANDS)   // 144 output rows per block
#define RB_ROWS 58          // band window: 48 outputs + 10 halo
#define RB_STRIDE 36        // LDS row stride (floats): 32 data + 4 pad
#define NTX 16              // 512/32 column strips
#define NSTRIP 4            // 4 row strips of 144 (576 >= 502; last bands break)
#define NBLOCKS (NTX * NSTRIP * BATCH)   // 2048
#define N1 ((double)BATCH * H * W)            // MSE denom
#define N2 ((double)BATCH * OUT_HW * OUT_HW)  // SSIM denom

struct GaussW { float g[11]; };

// Launch-bounds history (do not re-break this):
//   (256,3) R1: VGPR cap 170 -> spill disaster; (256,4) R3: 64-VGPR dive, 2 GB scratch
//   (256,2) R2..R10: sane (VGPR 52-68, WRITE ~64 B).
// R9 (high occ 6 blk/CU, DS 12/out) = 48 us; R10 (low occ 3 blk/CU, DS 7/out)
// = 48 us: the two factors trade ~1:1. R11 tests the unexplored quadrant:
// BAND=48 -> stage B 3r x 2c = 256 items (all threads), DS 8.67/out, LDS
// 32.6 KB -> 4 blocks/CU WITH VGPR<=128 (expect ~70). Grid 2048 unchanged.
__global__ __launch_bounds__(256, 2)
void ssim_strip_kernel(const float* __restrict__ pred,
                       const float* __restrict__ targ,
                       float* __restrict__ ws_contrib,
                       GaussW gw)
{
    __shared__ __align__(16) float rb[4][RB_ROWS * RB_STRIDE];
    __shared__ float red[8];

    const int tid = threadIdx.x;
    const int tx = blockIdx.x, sy = blockIdx.y, b = blockIdx.z;
    const int ox0 = tx * TS_X;
    const int S = sy * STRIP;                    // first output/input row of strip
    const int cols = min(TS_X, OUT_HW - ox0);    // valid output cols (32, or 22 for tx=15)
    const int mse_end = S + STRIP;               // strip owns input rows [S, min(S+144,512))
    const bool interior_x = (ox0 + 44 <= W);     // all 16-px windows in-bounds (tx<=14)

    const float* __restrict__ pb = pred + ((size_t)b << 18);
    const float* __restrict__ tb = targ + ((size_t)b << 18);

    // Stage-B per-thread constants (3 rows x 2 cols per thread, 256 items/band)
    const int br0 = 3 * (tid >> 4);
    const int bc0 = 2 * (tid & 15);

    float mse_local = 0.f, ssim_local = 0.f;

    #pragma unroll 1
    for (int band = 0; band < NBANDS; ++band) {
        const int out0 = S + band * BAND;              // first output row of band
        if (out0 >= OUT_HW) break;                     // block-uniform (last strip)
        const int brows = min(BAND, OUT_HW - out0);    // 48, or 22 (last band, last strip)
        const int h0    = (band == 0) ? S : (out0 + 10); // first NEW h-blur row
        const int h1    = min(out0 + brows + 10, H);     // end of new h-rows
        const int nnew  = h1 - h0;                       // 58 / 48 / less at edges
        const int slot0 = h0 - out0;                     // LDS slot of first new row (0 or 10)

        if (band > 0) {
            __syncthreads();            // previous stage B done reading
            // copy-down: slots 48..57 (rows out0..out0+9) -> slots 0..9
            if (tid < 80) {
                const int r = tid >> 3, q = (tid & 7) * 4;
                const int src = (BAND + r) * RB_STRIDE + q;
                const int dst = r * RB_STRIDE + q;
                float4 v0 = *(const float4*)&rb[0][src];
                float4 v1 = *(const float4*)&rb[1][src];
                float4 v2 = *(const float4*)&rb[2][src];
                float4 v3 = *(const float4*)&rb[3][src];
                *(float4*)&rb[0][dst] = v0;
                *(float4*)&rb[1][dst] = v1;
                *(float4*)&rb[2][dst] = v2;
                *(float4*)&rb[3][dst] = v3;
            }
            __syncthreads();            // copy visible before stage A overwrites 10..57
        }

        // ---- Stage A: h-blur the nnew new rows into slots slot0..slot0+nnew-1
        #pragma unroll 1
        for (int idx = tid; idx < nnew * 8; idx += 256) {
            const int r = idx >> 3, gq = idx & 7;
            const int c0 = 4 * gq;
            const int gy = h0 + r;                      // < H by construction
            const int base = (gy << 9) + ox0 + c0;      // 32-bit element offset
            float sv[16], dv[16], ss[16], dd[16];
            if (interior_x) {           // block-uniform branch: no divergence
                #pragma unroll
                for (int q = 0; q < 4; ++q) {
                    *(float4*)(sv + 4 * q) = *(const float4*)(pb + base + 4 * q);
                    *(float4*)(dv + 4 * q) = *(const float4*)(tb + base + 4 * q);
                }
            } else {
                #pragma unroll
                for (int q = 0; q < 4; ++q) {
                    int gx = ox0 + c0 + 4 * q;
                    float4 vp = make_float4(0.f, 0.f, 0.f, 0.f);
                    float4 vt = vp;
                    if (gx < W) {       // 16B-aligned: all-or-nothing
                        vp = *(const float4*)(pb + base + 4 * q);
                        vt = *(const float4*)(tb + base + 4 * q);
                    }
                    *(float4*)(sv + 4 * q) = vp;
                    *(float4*)(dv + 4 * q) = vt;
                }
            }
            #pragma unroll
            for (int i = 0; i < 16; ++i) {
                float p = sv[i], t = dv[i];
                float s = p + t, d = p - t;
                sv[i] = s; dv[i] = d;
                ss[i] = s * s; dd[i] = d * d;
            }

            // MSE: strip owns input rows [S, min(S+STRIP,H)); each h-row once.
            // First f4 (cols ox0+c0..+3) = exact x-cover across the 8 groups.
            if (gy < mse_end)
                mse_local += dd[0] + dd[1] + dd[2] + dd[3];

            float a[4][4] = {};
            #pragma unroll
            for (int k = 0; k < 11; ++k) {
                float g = gw.g[k];
                #pragma unroll
                for (int j = 0; j < 4; ++j) {
                    a[0][j] = fmaf(g, sv[j + k], a[0][j]);
                    a[1][j] = fmaf(g, dv[j + k], a[1][j]);
                    a[2][j] = fmaf(g, ss[j + k], a[2][j]);
                    a[3][j] = fmaf(g, dd[j + k], a[3][j]);
                }
            }
            const int wr = (slot0 + r) * RB_STRIDE + c0;
            #pragma unroll
            for (int ch = 0; ch < 4; ++ch)
                *(float4*)(&rb[ch][wr]) = make_float4(a[ch][0], a[ch][1], a[ch][2], a[ch][3]);
        }
        __syncthreads();

        // ---- Stage B: vertical blur, 3 rows x 2 cols per thread (slots 0..57)
        if (br0 < brows) {
            float acc[4][3][2] = {};   // [ch][row i][col j]
            #pragma unroll
            for (int jr = 0; jr < 13; ++jr) {
                int rr = br0 + jr;
                #pragma unroll
                for (int ch = 0; ch < 4; ++ch) {
                    float2 v = *(const float2*)(&rb[ch][rr * RB_STRIDE + bc0]);
                    #pragma unroll
                    for (int i = 0; i < 3; ++i) {
                        int k = jr - i;
                        if (k >= 0 && k < 11) {
                            float g = gw.g[k];
                            acc[ch][i][0] = fmaf(g, v.x, acc[ch][i][0]);
                            acc[ch][i][1] = fmaf(g, v.y, acc[ch][i][1]);
                        }
                    }
                }
            }
            const float C1 = 1e-4f, C2 = 9e-4f;
            #pragma unroll
            for (int i = 0; i < 3; ++i) {
                if (br0 + i < brows) {
                    #pragma unroll
                    for (int j = 0; j < 2; ++j) {
                        if (bc0 + j < cols) {
                            float A  = acc[0][i][j], Bv = acc[1][i][j];
                            float U  = acc[2][i][j], V  = acc[3][i][j];
                            float A2 = A * A, B2 = Bv * Bv;
                            float mu12_2 = 0.5f * (A2 - B2);      // 2*mu1*mu2
                            float musq   = 0.5f * (A2 + B2);      // mu1^2+mu2^2
                            float sig12_2 = 0.5f * (U - V) - mu12_2;
                            float sigsum  = 0.5f * (U + V) - musq;
                            float num = (mu12_2 + C1) * (sig12_2 + C2);
                            float den = (musq + C1) * (sigsum + C2) + 1e-6f;
                            ssim_local += num / den;
                        }
                    }
                }
            }
        }
        // WAR hazard vs next band's copy/A handled by loop-top barrier
    }

    // ---- Block reduction (once per block; 256 threads = 4 waves)
    #pragma unroll
    for (int off = 32; off > 0; off >>= 1) {
        ssim_local += __shfl_down(ssim_local, off, 64);
        mse_local  += __shfl_down(mse_local,  off, 64);
    }
    int wave = tid >> 6;
    if ((tid & 63) == 0) { red[wave] = ssim_local; red[4 + wave] = mse_local; }
    __syncthreads();
    if (tid == 0) {
        float s = red[0] + red[1] + red[2] + red[3];
        float m = red[4] + red[5] + red[6] + red[7];
        double contrib = 0.6 * (double)m / N1 - 0.4 * (double)s / N2;
        int bid = (b * NSTRIP + sy) * NTX + tx;
        ws_contrib[bid] = (float)contrib;
    }
}

__global__ __launch_bounds__(1024)
void finalize_kernel(const float* __restrict__ ws_contrib,
                     float* __restrict__ out)
{
    __shared__ double rs[1024];
    int tid = threadIdx.x;
    double s = 0.0;
    for (int i = tid; i < NBLOCKS; i += 1024)
        s += (double)ws_contrib[i];
    rs[tid] = s;
    __syncthreads();
    for (int off = 512; off > 0; off >>= 1) {
        if (tid < off) rs[tid] += rs[tid + off];
        __syncthreads();
    }
    if (tid == 0)
        out[0] = (float)(0.4 + rs[0]);
}

extern "C" void kernel_launch(void* const* d_in, const int* in_sizes, int n_in,
                              void* d_out, int out_size, void* d_ws, size_t ws_size,
                              hipStream_t stream)
{
    const float* pred = (const float*)d_in[0];
    const float* targ = (const float*)d_in[1];
    float* out = (float*)d_out;
    float* ws_contrib = (float*)d_ws;

    // Gaussian taps: computed host-side in double, normalized, passed by value.
    GaussW gw;
    double g[11], sum = 0.0;
    for (int i = 0; i < 11; ++i) { double x = i - 5.0; g[i] = exp(-x * x / 4.5); sum += g[i]; }
    for (int i = 0; i < 11; ++i) gw.g[i] = (float)(g[i] / sum);

    ssim_strip_kernel<<<dim3(NTX, NSTRIP, BATCH), 256, 0, stream>>>(pred, targ, ws_contrib, gw);
    finalize_kernel<<<1, 1024, 0, stream>>>(ws_contrib, out);
}

// Round 12
// 120.379 us; speedup vs baseline: 1.0409x; 1.0409x over previous
//
#include <hip/hip_runtime.h>
#include <hip/hip_fp16.h>
#include <math.h>

// Problem constants
#define BATCH 32
#define H 512
#define W 512
#define OUT_HW 502          // 512 - 11 + 1
#define TS_X 32             // output strip width
#define BAND 48             // output rows per band
#define NBANDS 3
#define STRIP (BAND * NBANDS)   // 144 output rows per block
#define RB_ROWS 58          // band window: 48 outputs + 10 halo
#define NTX 16              // 512/32 column strips
#define NSTRIP 4            // 4 row strips of 144 (576 >= 502; last bands break)
#define NBLOCKS (NTX * NSTRIP * BATCH)   // 2048
#define N1 ((double)BATCH * H * W)            // MSE denom
#define N2 ((double)BATCH * OUT_HW * OUT_HW)  // SSIM denom

struct GaussW { float g[11]; };

// Launch-bounds history (do not re-break this):
//   (256,3) R1: VGPR cap 170 -> spill disaster; (256,4) R3: 64-VGPR dive, 2 GB scratch
//   (256,2) R2..R11: sane (VGPR 52-68, WRITE ~64 B).
// R8-R11 plateau 48-52 us across occ/DS/barrier variants: co-limited VALU+DS.
// R12: (a) channel-interleaved LDS: rbh[(row*16+cp)*4+ch] as __half2 -> stage B
// reads ONE ds_read_b128 per (jr,thread) = 2.2 DS/output (was 8.7); LDS 14.8 KB.
// (b) fp16 v-blur via __hfma2 (2 cols/instr): 22 FMA-instr/output (was 44).
// H-blur stays fp32 (exact taps); MSE fp32. Expected absmax ~1e-4..1e-3 << 1e-2.
__global__ __launch_bounds__(256, 2)
void ssim_strip_kernel(const float* __restrict__ pred,
                       const float* __restrict__ targ,
                       float* __restrict__ ws_contrib,
                       GaussW gw)
{
    __shared__ __align__(16) __half2 rbh[RB_ROWS * 16 * 4];  // [row][colpair][ch]
    __shared__ float red[8];

    const int tid = threadIdx.x;
    const int tx = blockIdx.x, sy = blockIdx.y, b = blockIdx.z;
    const int ox0 = tx * TS_X;
    const int S = sy * STRIP;                    // first output/input row of strip
    const int cols = min(TS_X, OUT_HW - ox0);    // valid output cols (32, or 22 for tx=15)
    const int mse_end = S + STRIP;               // strip owns input rows [S, min(S+144,512))
    const bool interior_x = (ox0 + 44 <= W);     // all 16-px windows in-bounds (tx<=14)

    const float* __restrict__ pb = pred + ((size_t)b << 18);
    const float* __restrict__ tb = targ + ((size_t)b << 18);

    // fp16 taps for the v-blur (h-blur keeps exact fp32 taps)
    __half2 gh2[11];
    #pragma unroll
    for (int k = 0; k < 11; ++k) gh2[k] = __float2half2_rn(gw.g[k]);

    // Stage-B per-thread constants (3 rows x 1 colpair (2 cols), 256 items/band)
    const int br0 = 3 * (tid >> 4);
    const int cp  = tid & 15;
    const int bc0 = 2 * cp;

    float mse_local = 0.f, ssim_local = 0.f;

    #pragma unroll 1
    for (int band = 0; band < NBANDS; ++band) {
        const int out0 = S + band * BAND;              // first output row of band
        if (out0 >= OUT_HW) break;                     // block-uniform (last strip)
        const int brows = min(BAND, OUT_HW - out0);    // 48, or 22 (last band, last strip)
        const int h0    = (band == 0) ? S : (out0 + 10); // first NEW h-blur row
        const int h1    = min(out0 + brows + 10, H);     // end of new h-rows
        const int nnew  = h1 - h0;                       // 58 / 48 / less at edges
        const int slot0 = h0 - out0;                     // LDS slot of first new row (0 or 10)

        if (band > 0) {
            __syncthreads();            // previous stage B done reading
            // copy-down: slots 48..57 (rows out0..out0+9) -> slots 0..9
            // 10 rows x 16 colpairs, one b128 (all 4 channels) per item
            if (tid < 160) {
                const int r = tid >> 4, q = tid & 15;
                *(float4*)&rbh[(r * 16 + q) * 4] =
                    *(const float4*)&rbh[((BAND + r) * 16 + q) * 4];
            }
            __syncthreads();            // copy visible before stage A overwrites 10..57
        }

        // ---- Stage A: h-blur the nnew new rows into slots slot0..slot0+nnew-1
        #pragma unroll 1
        for (int idx = tid; idx < nnew * 8; idx += 256) {
            const int r = idx >> 3, gq = idx & 7;
            const int c0 = 4 * gq;
            const int gy = h0 + r;                      // < H by construction
            const int base = (gy << 9) + ox0 + c0;      // 32-bit element offset
            float sv[16], dv[16], ss[16], dd[16];
            if (interior_x) {           // block-uniform branch: no divergence
                #pragma unroll
                for (int q = 0; q < 4; ++q) {
                    *(float4*)(sv + 4 * q) = *(const float4*)(pb + base + 4 * q);
                    *(float4*)(dv + 4 * q) = *(const float4*)(tb + base + 4 * q);
                }
            } else {
                #pragma unroll
                for (int q = 0; q < 4; ++q) {
                    int gx = ox0 + c0 + 4 * q;
                    float4 vp = make_float4(0.f, 0.f, 0.f, 0.f);
                    float4 vt = vp;
                    if (gx < W) {       // 16B-aligned: all-or-nothing
                        vp = *(const float4*)(pb + base + 4 * q);
                        vt = *(const float4*)(tb + base + 4 * q);
                    }
                    *(float4*)(sv + 4 * q) = vp;
                    *(float4*)(dv + 4 * q) = vt;
                }
            }
            #pragma unroll
            for (int i = 0; i < 16; ++i) {
                float p = sv[i], t = dv[i];
                float s = p + t, d = p - t;
                sv[i] = s; dv[i] = d;
                ss[i] = s * s; dd[i] = d * d;
            }

            // MSE: strip owns input rows [S, min(S+STRIP,H)); each h-row once.
            // First f4 (cols ox0+c0..+3) = exact x-cover across the 8 groups.
            if (gy < mse_end)
                mse_local += dd[0] + dd[1] + dd[2] + dd[3];

            float a[4][4] = {};
            #pragma unroll
            for (int k = 0; k < 11; ++k) {
                float g = gw.g[k];
                #pragma unroll
                for (int j = 0; j < 4; ++j) {
                    a[0][j] = fmaf(g, sv[j + k], a[0][j]);
                    a[1][j] = fmaf(g, dv[j + k], a[1][j]);
                    a[2][j] = fmaf(g, ss[j + k], a[2][j]);
                    a[3][j] = fmaf(g, dd[j + k], a[3][j]);
                }
            }
            // pack to half2, channel-interleaved: one b128 per colpair
            const int row = slot0 + r;
            #pragma unroll
            for (int cpl = 0; cpl < 2; ++cpl) {
                __align__(16) __half2 hw[4];
                #pragma unroll
                for (int ch = 0; ch < 4; ++ch)
                    hw[ch] = __floats2half2_rn(a[ch][2 * cpl], a[ch][2 * cpl + 1]);
                *(float4*)&rbh[(row * 16 + (2 * gq + cpl)) * 4] = *(const float4*)hw;
            }
        }
        __syncthreads();

        // ---- Stage B: fp16 vertical blur, 3 rows x 2 cols (one colpair) per thread
        if (br0 < brows) {
            __half2 acc[4][3];
            #pragma unroll
            for (int ch = 0; ch < 4; ++ch)
                #pragma unroll
                for (int i = 0; i < 3; ++i) acc[ch][i] = __float2half2_rn(0.f);

            #pragma unroll
            for (int jr = 0; jr < 13; ++jr) {
                const int rr = br0 + jr;
                __align__(16) __half2 hv[4];
                *(float4*)hv = *(const float4*)&rbh[(rr * 16 + cp) * 4];
                #pragma unroll
                for (int ch = 0; ch < 4; ++ch) {
                    #pragma unroll
                    for (int i = 0; i < 3; ++i) {
                        const int k = jr - i;
                        if (k >= 0 && k < 11)
                            acc[ch][i] = __hfma2(gh2[k], hv[ch], acc[ch][i]);
                    }
                }
            }
            const float C1 = 1e-4f, C2 = 9e-4f;
            #pragma unroll
            for (int i = 0; i < 3; ++i) {
                if (br0 + i < brows) {
                    #pragma unroll
                    for (int j = 0; j < 2; ++j) {
                        if (bc0 + j < cols) {
                            float A, Bv, U, V;
                            if (j == 0) {
                                A = __low2float(acc[0][i]);  Bv = __low2float(acc[1][i]);
                                U = __low2float(acc[2][i]);  V  = __low2float(acc[3][i]);
                            } else {
                                A = __high2float(acc[0][i]); Bv = __high2float(acc[1][i]);
                                U = __high2float(acc[2][i]); V  = __high2float(acc[3][i]);
                            }
                            float A2 = A * A, B2 = Bv * Bv;
                            float mu12_2 = 0.5f * (A2 - B2);      // 2*mu1*mu2
                            float musq   = 0.5f * (A2 + B2);      // mu1^2+mu2^2
                            float sig12_2 = 0.5f * (U - V) - mu12_2;
                            float sigsum  = 0.5f * (U + V) - musq;
                            float num = (mu12_2 + C1) * (sig12_2 + C2);
                            float den = (musq + C1) * (sigsum + C2) + 1e-6f;
                            ssim_local += num / den;
                        }
                    }
                }
            }
        }
        // WAR hazard vs next band's copy/A handled by loop-top barrier
    }

    // ---- Block reduction (once per block; 256 threads = 4 waves)
    #pragma unroll
    for (int off = 32; off > 0; off >>= 1) {
        ssim_local += __shfl_down(ssim_local, off, 64);
        mse_local  += __shfl_down(mse_local,  off, 64);
    }
    int wave = tid >> 6;
    if ((tid & 63) == 0) { red[wave] = ssim_local; red[4 + wave] = mse_local; }
    __syncthreads();
    if (tid == 0) {
        float s = red[0] + red[1] + red[2] + red[3];
        float m = red[4] + red[5] + red[6] + red[7];
        double contrib = 0.6 * (double)m / N1 - 0.4 * (double)s / N2;
        int bid = (b * NSTRIP + sy) * NTX + tx;
        ws_contrib[bid] = (float)contrib;
    }
}

__global__ __launch_bounds__(1024)
void finalize_kernel(const float* __restrict__ ws_contrib,
                     float* __restrict__ out)
{
    __shared__ double rs[1024];
    int tid = threadIdx.x;
    double s = 0.0;
    for (int i = tid; i < NBLOCKS; i += 1024)
        s += (double)ws_contrib[i];
    rs[tid] = s;
    __syncthreads();
    for (int off = 512; off > 0; off >>= 1) {
        if (tid < off) rs[tid] += rs[tid + off];
        __syncthreads();
    }
    if (tid == 0)
        out[0] = (float)(0.4 + rs[0]);
}

extern "C" void kernel_launch(void* const* d_in, const int* in_sizes, int n_in,
                              void* d_out, int out_size, void* d_ws, size_t ws_size,
                              hipStream_t stream)
{
    const float* pred = (const float*)d_in[0];
    const float* targ = (const float*)d_in[1];
    float* out = (float*)d_out;
    float* ws_contrib = (float*)d_ws;

    // Gaussian taps: computed host-side in double, normalized, passed by value.
    GaussW gw;
    double g[11], sum = 0.0;
    for (int i = 0; i < 11; ++i) { double x = i - 5.0; g[i] = exp(-x * x / 4.5); sum += g[i]; }
    for (int i = 0; i < 11; ++i) gw.g[i] = (float)(g[i] / sum);

    ssim_strip_kernel<<<dim3(NTX, NSTRIP, BATCH), 256, 0, stream>>>(pred, targ, ws_contrib, gw);
    finalize_kernel<<<1, 1024, 0, stream>>>(ws_contrib, out);
}

// Round 15
// 110.848 us; speedup vs baseline: 1.1304x; 1.0860x over previous
//
#include <hip/hip_runtime.h>
#include <math.h>

// Problem constants
#define BATCH 32
#define H 512
#define W 512
#define OUT_HW 502           // 512 - 11 + 1
#define TS_X 32              // output strip width
#define BAND 32              // output rows per band
#define NBANDS 4
#define STRIP (BAND * NBANDS)    // 128 output rows per block
#define NTX 16
#define NSTRIP 4
#define NBLOCKS (NTX * NSTRIP * BATCH)   // 2048
#define N1 ((double)BATCH * H * W)
#define N2 ((double)BATCH * OUT_HW * OUT_HW)

struct GaussW { float g[11]; };

typedef _Float16 h8  __attribute__((ext_vector_type(8)));
typedef __fp16   h2t __attribute__((ext_vector_type(2)));   // cvt_pkrtz result type
typedef float    f4t __attribute__((ext_vector_type(4)));

// Launch-bounds history (do not re-break this):
//   (256,3) R1 and (256,4) R3: catastrophic spill. (256,2) R2..R14: sane.
// R8-R12 plateau 44-52 us: VALU-issue ~23 us is the wall, MfmaUtil 0.
// R13..R15: both 11-tap blurs as banded-Toeplitz MFMA (mfma_f32_16x16x32_f16).
// Constant G-fragment B[k][n]=g[k-n] shared by h- and v-blur; raw ring
// (mod 48); rbt transposed [col][slot] so v-blur A-frags are k-contiguous.
// R14 NaN lesson: zero-weight MFMA taps still propagate NaN (0*NaN=NaN) --
// every LDS location an MFMA touches MUST be written or zeroed. R15 zero-fills
// raw+rbt once at block start (covers band-0 ring slots 42-47 and tx=15's
// never-written px 32-47).
__global__ __launch_bounds__(256, 2)
void ssim_mfma_kernel(const float* __restrict__ pred,
                      const float* __restrict__ targ,
                      float* __restrict__ ws_contrib,
                      GaussW gw)
{
    __shared__ __align__(16) _Float16 raw[4][48 * 48];  // [ch][rowslot*48 + px]
    __shared__ __align__(16) _Float16 rbt[4][32 * 48];  // [ch][col*48 + slot]
    __shared__ float red[8];

    const int tid = threadIdx.x;
    const int tx = blockIdx.x, sy = blockIdx.y, b = blockIdx.z;
    const int ox0 = tx * TS_X;
    const int S = sy * STRIP;
    const int cols = min(TS_X, OUT_HW - ox0);     // 32, or 22 for tx=15
    const int mse_end = S + STRIP;                // strip owns input rows [S, S+128)
    const bool interior_x = (ox0 + 48 <= W);      // full 48-px window in-bounds (tx<=14)

    const float* __restrict__ pb = pred + ((size_t)b << 18);
    const float* __restrict__ tb = targ + ((size_t)b << 18);

    const int lane = tid & 63, wave = tid >> 6;
    const int quad = lane >> 4, nn = lane & 15, quad8 = quad << 3;

    // ---- Zero-fill all MFMA-visible LDS (NaN defense; see header comment).
    {
        _Float16* base = &raw[0][0];   // raw then rbt are contiguous decls; zero both
        const int total = 4 * 48 * 48; // raw halfs
        for (int i = tid * 8; i < total; i += 256 * 8)
            *(f4t*)(base + i) = f4t{0.f, 0.f, 0.f, 0.f};
        _Float16* base2 = &rbt[0][0];
        const int total2 = 4 * 32 * 48;
        for (int i = tid * 8; i < total2; i += 256 * 8)
            *(f4t*)(base2 + i) = f4t{0.f, 0.f, 0.f, 0.f};
    }
    __syncthreads();   // zeros visible before prep writes / h-blur reads

    // ---- Constant Toeplitz G fragment: B[k=quad8+j][n=nn] = g[k-n] (0 outside)
    h8 gfrag;
    #pragma unroll
    for (int j = 0; j < 8; ++j) {
        const int kk = quad8 + j - nn;
        float val = 0.f;
        #pragma unroll
        for (int t2 = 0; t2 < 11; ++t2) val = (kk == t2) ? gw.g[t2] : val;
        gfrag[j] = (_Float16)val;
    }
    const f4t zero4 = {0.f, 0.f, 0.f, 0.f};
    const float C1 = 1e-4f, C2 = 9e-4f;

    float mse_local = 0.f, ssim_local = 0.f;

    #pragma unroll 1
    for (int band = 0; band < NBANDS; ++band) {
        const int out0 = S + band * BAND;
        const int h0   = (band == 0) ? S : (out0 + 10);   // first NEW raw row
        const int h1   = min(out0 + 42, H);
        const int nnew = h1 - h0;                          // 42 / 32 / 22 (last)

        // ---- Prep: new raw rows -> fp16 {s, d, s^2, d^2}, ring slot = (gy-S) mod 48
        #pragma unroll 1
        for (int idx = tid; idx < nnew * 12; idx += 256) {
            const int r = idx / 12;
            const int g = idx - r * 12;
            const int gy = h0 + r;
            if (interior_x | (g < 8)) {
                const int base = (gy << 9) + ox0 + 4 * g;
                const f4t p = *(const f4t*)(pb + base);
                const f4t t = *(const f4t*)(tb + base);
                const f4t s = p + t, d = p - t;
                if ((g < 8) & (gy < mse_end))
                    mse_local += d[0]*d[0] + d[1]*d[1] + d[2]*d[2] + d[3]*d[3];
                int u = gy - S;                       // [0, 138)
                u -= (u >= 96) ? 96 : ((u >= 48) ? 48 : 0);
                const int off = u * 48 + 4 * g;
                // squares computed in fp32, then packed (no __fp16 arithmetic)
                h2t* w0 = (h2t*)&raw[0][off];
                w0[0] = __builtin_amdgcn_cvt_pkrtz(s[0], s[1]);
                w0[1] = __builtin_amdgcn_cvt_pkrtz(s[2], s[3]);
                h2t* w1 = (h2t*)&raw[1][off];
                w1[0] = __builtin_amdgcn_cvt_pkrtz(d[0], d[1]);
                w1[1] = __builtin_amdgcn_cvt_pkrtz(d[2], d[3]);
                h2t* w2 = (h2t*)&raw[2][off];
                w2[0] = __builtin_amdgcn_cvt_pkrtz(s[0]*s[0], s[1]*s[1]);
                w2[1] = __builtin_amdgcn_cvt_pkrtz(s[2]*s[2], s[3]*s[3]);
                h2t* w3 = (h2t*)&raw[3][off];
                w3[0] = __builtin_amdgcn_cvt_pkrtz(d[0]*d[0], d[1]*d[1]);
                w3[1] = __builtin_amdgcn_cvt_pkrtz(d[2]*d[2], d[3]*d[3]);
            }
        }
        __syncthreads();   // raw ready (also: all waves past last band's v-blur)

        // ---- H-blur via MFMA: 24 tiles (3 rowtiles x 2 coltiles x 4 ch), wave-strided
        #pragma unroll 1
        for (int t5 = wave; t5 < 24; t5 += 4) {
            const int ch = t5 & 3, rem = t5 >> 2;
            const int j0 = (rem & 1) << 4, r0 = (rem >> 1) << 4;
            int u = band * BAND + r0 + nn;            // raw ring row, [0, 144)
            u -= (u >= 96) ? 96 : ((u >= 48) ? 48 : 0);
            const h8 a = *(const h8*)&raw[ch][u * 48 + j0 + quad8];
            const f4t dacc = __builtin_amdgcn_mfma_f32_16x16x32_f16(a, gfrag, zero4, 0, 0, 0);
            // D[row=quad*4+reg][col=nn]: out col = j0+nn, out slot = r0+quad*4+reg
            h2t* wp = (h2t*)&rbt[ch][(j0 + nn) * 48 + r0 + (quad << 2)];
            wp[0] = __builtin_amdgcn_cvt_pkrtz(dacc[0], dacc[1]);
            wp[1] = __builtin_amdgcn_cvt_pkrtz(dacc[2], dacc[3]);
        }
        __syncthreads();   // rbt ready

        // ---- V-blur via MFMA (transposed) + SSIM epilogue: 1 out-tile per wave
        {
            const int c0 = (wave & 1) << 4, r0v = (wave >> 1) << 4;
            f4t dv[4];
            #pragma unroll
            for (int ch = 0; ch < 4; ++ch) {
                const h8 a = *(const h8*)&rbt[ch][(c0 + nn) * 48 + r0v + quad8];
                dv[ch] = __builtin_amdgcn_mfma_f32_16x16x32_f16(a, gfrag, zero4, 0, 0, 0);
            }
            // D[row=quad*4+reg][col=nn]: out row = out0+r0v+nn, out px col = c0+quad*4+reg
            const int rowg = out0 + r0v + nn;
            if (rowg < OUT_HW) {
                #pragma unroll
                for (int reg = 0; reg < 4; ++reg) {
                    const int cl = c0 + (quad << 2) + reg;
                    if (cl < cols) {
                        const float A = dv[0][reg], Bv = dv[1][reg];
                        const float U = dv[2][reg], V  = dv[3][reg];
                        const float A2 = A * A, B2 = Bv * Bv;
                        const float mu12_2 = 0.5f * (A2 - B2);   // 2*mu1*mu2
                        const float musq   = 0.5f * (A2 + B2);   // mu1^2+mu2^2
                        const float sig12_2 = 0.5f * (U - V) - mu12_2;
                        const float sigsum  = 0.5f * (U + V) - musq;
                        const float num = (mu12_2 + C1) * (sig12_2 + C2);
                        const float den = (musq + C1) * (sigsum + C2) + 1e-6f;
                        ssim_local += num * __builtin_amdgcn_rcpf(den);
                    }
                }
            }
        }
        // Next band's prep writes raw only (disjoint from rbt); the post-prep
        // barrier orders raw writes vs next h-blur reads, and the post-h-blur
        // barrier orders this band's v-blur reads vs next h-blur's rbt writes.
    }

    // ---- Block reduction (256 threads = 4 waves)
    #pragma unroll
    for (int off = 32; off > 0; off >>= 1) {
        ssim_local += __shfl_down(ssim_local, off, 64);
        mse_local  += __shfl_down(mse_local,  off, 64);
    }
    if ((tid & 63) == 0) { red[wave] = ssim_local; red[4 + wave] = mse_local; }
    __syncthreads();
    if (tid == 0) {
        const float s = red[0] + red[1] + red[2] + red[3];
        const float m = red[4] + red[5] + red[6] + red[7];
        const double contrib = 0.6 * (double)m / N1 - 0.4 * (double)s / N2;
        const int bid = (b * NSTRIP + sy) * NTX + tx;
        ws_contrib[bid] = (float)contrib;
    }
}

__global__ __launch_bounds__(1024)
void finalize_kernel(const float* __restrict__ ws_contrib,
                     float* __restrict__ out)
{
    __shared__ double rs[1024];
    int tid = threadIdx.x;
    double s = 0.0;
    for (int i = tid; i < NBLOCKS; i += 1024)
        s += (double)ws_contrib[i];
    rs[tid] = s;
    __syncthreads();
    for (int off = 512; off > 0; off >>= 1) {
        if (tid < off) rs[tid] += rs[tid + off];
        __syncthreads();
    }
    if (tid == 0)
        out[0] = (float)(0.4 + rs[0]);
}

extern "C" void kernel_launch(void* const* d_in, const int* in_sizes, int n_in,
                              void* d_out, int out_size, void* d_ws, size_t ws_size,
                              hipStream_t stream)
{
    const float* pred = (const float*)d_in[0];
    const float* targ = (const float*)d_in[1];
    float* out = (float*)d_out;
    float* ws_contrib = (float*)d_ws;

    // Gaussian taps: computed host-side in double, normalized, passed by value.
    GaussW gw;
    double g[11], sum = 0.0;
    for (int i = 0; i < 11; ++i) { double x = i - 5.0; g[i] = exp(-x * x / 4.5); sum += g[i]; }
    for (int i = 0; i < 11; ++i) gw.g[i] = (float)(g[i] / sum);

    ssim_mfma_kernel<<<dim3(NTX, NSTRIP, BATCH), 256, 0, stream>>>(pred, targ, ws_contrib, gw);
    finalize_kernel<<<1, 1024, 0, stream>>>(ws_contrib, out);
}

// Round 16
// 108.469 us; speedup vs baseline: 1.1552x; 1.0219x over previous
//
#include <hip/hip_runtime.h>
#include <math.h>

// Problem constants
#define BATCH 32
#define H 512
#define W 512
#define OUT_HW 502           // 512 - 11 + 1
#define TS_X 32              // output strip width
#define BAND 32              // output rows per band
#define NBANDS 4
#define STRIP (BAND * NBANDS)    // 128 output rows per block
#define NTX 16
#define NSTRIP 4
#define NBLOCKS (NTX * NSTRIP * BATCH)   // 2048
#define N1 ((double)BATCH * H * W)
#define N2 ((double)BATCH * OUT_HW * OUT_HW)

struct GaussW { float g[11]; };

typedef _Float16 h8  __attribute__((ext_vector_type(8)));
typedef __fp16   h2t __attribute__((ext_vector_type(2)));   // cvt_pkrtz result type
typedef float    f4t __attribute__((ext_vector_type(4)));

// Launch-bounds history (do not re-break this):
//   (256,3) R1 and (256,4) R3: catastrophic spill. (256,2) R2..R15: sane.
// R13..R15: both 11-tap blurs as banded-Toeplitz MFMA (mfma_f32_16x16x32_f16),
// shared G-fragment B[k][n]=g[k-n]; raw ring (mod 48); rbt transposed
// [col][slot]. R14 NaN lesson: zero-weight MFMA taps still propagate NaN
// (0*NaN=NaN) -- every MFMA-read LDS location must be written or zeroed
// (raw zero-filled once; rbt fully written by h-blur before each v-blur read).
// R15 passed (absmax 0.0), kernel ~35 us (below the 41-us harness fill kernels
// -> counter-blind). R16: fp16-packed prep (v_pk_add/sub/mul on __fp16x2,
// 8-px items, one item/thread, b128 LDS writes) -- ~45% prep-VALU cut.
__global__ __launch_bounds__(256, 2)
void ssim_mfma_kernel(const float* __restrict__ pred,
                      const float* __restrict__ targ,
                      float* __restrict__ ws_contrib,
                      GaussW gw)
{
    __shared__ __align__(16) _Float16 raw[4][48 * 48];  // [ch][rowslot*48 + px]
    __shared__ __align__(16) _Float16 rbt[4][32 * 48];  // [ch][col*48 + slot]
    __shared__ float red[8];

    const int tid = threadIdx.x;
    const int tx = blockIdx.x, sy = blockIdx.y, b = blockIdx.z;
    const int ox0 = tx * TS_X;
    const int S = sy * STRIP;
    const int cols = min(TS_X, OUT_HW - ox0);     // 32, or 22 for tx=15
    const int mse_end = S + STRIP;                // strip owns input rows [S, S+128)
    const bool interior_x = (ox0 + 48 <= W);      // full 48-px window in-bounds (tx<=14)

    const float* __restrict__ pb = pred + ((size_t)b << 18);
    const float* __restrict__ tb = targ + ((size_t)b << 18);

    const int lane = tid & 63, wave = tid >> 6;
    const int quad = lane >> 4, nn = lane & 15, quad8 = quad << 3;

    // ---- Zero-fill raw (NaN defense: band-0 ring slots 42-47 and tx=15's
    // px 32-47 are MFMA-read but never written). rbt needs no fill: h-blur
    // writes every slot/col the v-blur reads, every band, before the read.
    {
        _Float16* base = &raw[0][0];
        const int total = 4 * 48 * 48;
        for (int i = tid * 8; i < total; i += 256 * 8)
            *(f4t*)(base + i) = f4t{0.f, 0.f, 0.f, 0.f};
    }

    // ---- Constant Toeplitz G fragment: B[k=quad8+j][n=nn] = g[k-n] (0 outside)
    h8 gfrag;
    #pragma unroll
    for (int j = 0; j < 8; ++j) {
        const int kk = quad8 + j - nn;
        float val = 0.f;
        #pragma unroll
        for (int t2 = 0; t2 < 11; ++t2) val = (kk == t2) ? gw.g[t2] : val;
        gfrag[j] = (_Float16)val;
    }
    const f4t zero4 = {0.f, 0.f, 0.f, 0.f};
    const float C1 = 1e-4f, C2 = 9e-4f;

    float mse_local = 0.f, ssim_local = 0.f;

    __syncthreads();   // zeros visible before h-blur reads

    #pragma unroll 1
    for (int band = 0; band < NBANDS; ++band) {
        const int out0 = S + band * BAND;
        const int h0   = (band == 0) ? S : (out0 + 10);   // first NEW raw row
        const int h1   = min(out0 + 42, H);
        const int nnew = h1 - h0;                          // 42 / 32 / 22 (last)

        // ---- Prep: fp16-packed. One 8-px item per thread (nnew*6 <= 252).
        // item: r = tid/6 (row), g = tid%6 (8-px group); groups 0-3 owned cols.
        if (tid < nnew * 6) {
            const int r = tid / 6;
            const int g = tid - r * 6;
            const int gy = h0 + r;
            if (interior_x | (g < 4)) {
                const int base = (gy << 9) + ox0 + 8 * g;
                const f4t p0 = *(const f4t*)(pb + base);
                const f4t p1 = *(const f4t*)(pb + base + 4);
                const f4t t0 = *(const f4t*)(tb + base);
                const f4t t1 = *(const f4t*)(tb + base + 4);
                const h2t hp0 = __builtin_amdgcn_cvt_pkrtz(p0[0], p0[1]);
                const h2t hp1 = __builtin_amdgcn_cvt_pkrtz(p0[2], p0[3]);
                const h2t hp2 = __builtin_amdgcn_cvt_pkrtz(p1[0], p1[1]);
                const h2t hp3 = __builtin_amdgcn_cvt_pkrtz(p1[2], p1[3]);
                const h2t ht0 = __builtin_amdgcn_cvt_pkrtz(t0[0], t0[1]);
                const h2t ht1 = __builtin_amdgcn_cvt_pkrtz(t0[2], t0[3]);
                const h2t ht2 = __builtin_amdgcn_cvt_pkrtz(t1[0], t1[1]);
                const h2t ht3 = __builtin_amdgcn_cvt_pkrtz(t1[2], t1[3]);
                __align__(16) h2t sv[4], dv[4], ssv[4], ddv[4];
                sv[0] = hp0 + ht0; sv[1] = hp1 + ht1; sv[2] = hp2 + ht2; sv[3] = hp3 + ht3;
                dv[0] = hp0 - ht0; dv[1] = hp1 - ht1; dv[2] = hp2 - ht2; dv[3] = hp3 - ht3;
                ssv[0] = sv[0] * sv[0]; ssv[1] = sv[1] * sv[1];
                ssv[2] = sv[2] * sv[2]; ssv[3] = sv[3] * sv[3];
                ddv[0] = dv[0] * dv[0]; ddv[1] = dv[1] * dv[1];
                ddv[2] = dv[2] * dv[2]; ddv[3] = dv[3] * dv[3];

                // MSE over owned px (groups 0-3 = cols ox0..ox0+31), owned rows
                if ((g < 4) & (gy < mse_end)) {
                    const h2t macc = (ddv[0] + ddv[1]) + (ddv[2] + ddv[3]);
                    mse_local += (float)macc[0] + (float)macc[1];
                }

                int u = gy - S;                       // [0, 138)
                u -= (u >= 96) ? 96 : ((u >= 48) ? 48 : 0);
                const int off = u * 48 + 8 * g;
                *(f4t*)&raw[0][off] = *(const f4t*)sv;
                *(f4t*)&raw[1][off] = *(const f4t*)dv;
                *(f4t*)&raw[2][off] = *(const f4t*)ssv;
                *(f4t*)&raw[3][off] = *(const f4t*)ddv;
            }
        }
        __syncthreads();   // raw ready (also: all waves past last band's v-blur)

        // ---- H-blur via MFMA: 24 tiles (3 rowtiles x 2 coltiles x 4 ch), wave-strided
        #pragma unroll 1
        for (int t5 = wave; t5 < 24; t5 += 4) {
            const int ch = t5 & 3, rem = t5 >> 2;
            const int j0 = (rem & 1) << 4, r0 = (rem >> 1) << 4;
            int u = band * BAND + r0 + nn;            // raw ring row, [0, 144)
            u -= (u >= 96) ? 96 : ((u >= 48) ? 48 : 0);
            const h8 a = *(const h8*)&raw[ch][u * 48 + j0 + quad8];
            const f4t dacc = __builtin_amdgcn_mfma_f32_16x16x32_f16(a, gfrag, zero4, 0, 0, 0);
            // D[row=quad*4+reg][col=nn]: out col = j0+nn, out slot = r0+quad*4+reg
            h2t* wp = (h2t*)&rbt[ch][(j0 + nn) * 48 + r0 + (quad << 2)];
            wp[0] = __builtin_amdgcn_cvt_pkrtz(dacc[0], dacc[1]);
            wp[1] = __builtin_amdgcn_cvt_pkrtz(dacc[2], dacc[3]);
        }
        __syncthreads();   // rbt ready

        // ---- V-blur via MFMA (transposed) + SSIM epilogue: 1 out-tile per wave
        {
            const int c0 = (wave & 1) << 4, r0v = (wave >> 1) << 4;
            f4t dv2[4];
            #pragma unroll
            for (int ch = 0; ch < 4; ++ch) {
                const h8 a = *(const h8*)&rbt[ch][(c0 + nn) * 48 + r0v + quad8];
                dv2[ch] = __builtin_amdgcn_mfma_f32_16x16x32_f16(a, gfrag, zero4, 0, 0, 0);
            }
            // D[row=quad*4+reg][col=nn]: out row = out0+r0v+nn, out px col = c0+quad*4+reg
            const int rowg = out0 + r0v + nn;
            if (rowg < OUT_HW) {
                #pragma unroll
                for (int reg = 0; reg < 4; ++reg) {
                    const int cl = c0 + (quad << 2) + reg;
                    if (cl < cols) {
                        const float A = dv2[0][reg], Bv = dv2[1][reg];
                        const float U = dv2[2][reg], V  = dv2[3][reg];
                        const float A2 = A * A, B2 = Bv * Bv;
                        const float mu12_2 = 0.5f * (A2 - B2);   // 2*mu1*mu2
                        const float musq   = 0.5f * (A2 + B2);   // mu1^2+mu2^2
                        const float sig12_2 = 0.5f * (U - V) - mu12_2;
                        const float sigsum  = 0.5f * (U + V) - musq;
                        const float num = (mu12_2 + C1) * (sig12_2 + C2);
                        const float den = (musq + C1) * (sigsum + C2) + 1e-6f;
                        ssim_local += num * __builtin_amdgcn_rcpf(den);
                    }
                }
            }
        }
        // Next band's prep writes raw only (disjoint from rbt); the post-prep
        // barrier orders raw writes vs next h-blur reads, and the post-h-blur
        // barrier orders this band's v-blur reads vs next h-blur's rbt writes.
    }

    // ---- Block reduction (256 threads = 4 waves)
    #pragma unroll
    for (int off = 32; off > 0; off >>= 1) {
        ssim_local += __shfl_down(ssim_local, off, 64);
        mse_local  += __shfl_down(mse_local,  off, 64);
    }
    if ((tid & 63) == 0) { red[wave] = ssim_local; red[4 + wave] = mse_local; }
    __syncthreads();
    if (tid == 0) {
        const float s = red[0] + red[1] + red[2] + red[3];
        const float m = red[4] + red[5] + red[6] + red[7];
        const double contrib = 0.6 * (double)m / N1 - 0.4 * (double)s / N2;
        const int bid = (b * NSTRIP + sy) * NTX + tx;
        ws_contrib[bid] = (float)contrib;
    }
}

__global__ __launch_bounds__(1024)
void finalize_kernel(const float* __restrict__ ws_contrib,
                     float* __restrict__ out)
{
    __shared__ double rs[1024];
    int tid = threadIdx.x;
    double s = 0.0;
    for (int i = tid; i < NBLOCKS; i += 1024)
        s += (double)ws_contrib[i];
    rs[tid] = s;
    __syncthreads();
    for (int off = 512; off > 0; off >>= 1) {
        if (tid < off) rs[tid] += rs[tid + off];
        __syncthreads();
    }
    if (tid == 0)
        out[0] = (float)(0.4 + rs[0]);
}

extern "C" void kernel_launch(void* const* d_in, const int* in_sizes, int n_in,
                              void* d_out, int out_size, void* d_ws, size_t ws_size,
                              hipStream_t stream)
{
    const float* pred = (const float*)d_in[0];
    const float* targ = (const float*)d_in[1];
    float* out = (float*)d_out;
    float* ws_contrib = (float*)d_ws;

    // Gaussian taps: computed host-side in double, normalized, passed by value.
    GaussW gw;
    double g[11], sum = 0.0;
    for (int i = 0; i < 11; ++i) { double x = i - 5.0; g[i] = exp(-x * x / 4.5); sum += g[i]; }
    for (int i = 0; i < 11; ++i) gw.g[i] = (float)(g[i] / sum);

    ssim_mfma_kernel<<<dim3(NTX, NSTRIP, BATCH), 256, 0, stream>>>(pred, targ, ws_contrib, gw);
    finalize_kernel<<<1, 1024, 0, stream>>>(ws_contrib, out);
}

// Round 17
// 107.413 us; speedup vs baseline: 1.1666x; 1.0098x over previous
//
#include <hip/hip_runtime.h>
#include <math.h>

// Problem constants
#define BATCH 32
#define H 512
#define W 512
#define OUT_HW 502           // 512 - 11 + 1
#define TS_X 32              // output strip width
#define BAND 32              // output rows per band
#define NBANDS 4
#define STRIP (BAND * NBANDS)    // 128 output rows per block
#define NTX 16
#define NSTRIP 4
#define NBLOCKS (NTX * NSTRIP * BATCH)   // 2048
#define N1 ((double)BATCH * H * W)
#define N2 ((double)BATCH * OUT_HW * OUT_HW)

struct GaussW { float g[11]; };

typedef _Float16 h8  __attribute__((ext_vector_type(8)));
typedef __fp16   h2t __attribute__((ext_vector_type(2)));   // cvt_pkrtz result type
typedef float    f4t __attribute__((ext_vector_type(4)));

// Launch-bounds history (do not re-break this):
//   (256,3) R1 and (256,4) R3: catastrophic spill. (256,2) R2..R16: sane.
// R13..R16: both 11-tap blurs as banded-Toeplitz MFMA (mfma_f32_16x16x32_f16),
// shared G-fragment B[k][n]=g[k-n]; raw ring (mod 48); rbt transposed
// [col][slot]. R14 NaN lesson: zero-weight MFMA taps still propagate NaN
// (0*NaN=NaN) -- every MFMA-read LDS location must be written or zeroed.
// R16: fp16-packed prep (one 8-px item/thread). Kernel ~33 us, counter-blind
// (below the 41-us harness fill kernels).
// R17: software-pipelined global loads -- band n+1's p/t loads issue right
// after band n's prep, overlapping the h/v MFMA phases (hides the ~600-900 cyc
// band-start HBM/L2 latency). +16 VGPRs held across the band body.
__global__ __launch_bounds__(256, 2)
void ssim_mfma_kernel(const float* __restrict__ pred,
                      const float* __restrict__ targ,
                      float* __restrict__ ws_contrib,
                      GaussW gw)
{
    __shared__ __align__(16) _Float16 raw[4][48 * 48];  // [ch][rowslot*48 + px]
    __shared__ __align__(16) _Float16 rbt[4][32 * 48];  // [ch][col*48 + slot]
    __shared__ float red[8];

    const int tid = threadIdx.x;
    const int tx = blockIdx.x, sy = blockIdx.y, b = blockIdx.z;
    const int ox0 = tx * TS_X;
    const int S = sy * STRIP;
    const int cols = min(TS_X, OUT_HW - ox0);     // 32, or 22 for tx=15
    const int mse_end = S + STRIP;                // strip owns input rows [S, S+128)
    const bool interior_x = (ox0 + 48 <= W);      // full 48-px window in-bounds (tx<=14)

    const float* __restrict__ pb = pred + ((size_t)b << 18);
    const float* __restrict__ tb = targ + ((size_t)b << 18);

    const int lane = tid & 63, wave = tid >> 6;
    const int quad = lane >> 4, nn = lane & 15, quad8 = quad << 3;

    // Per-thread prep item geometry (fixed across bands): row r, 8-px group g
    const int pr = tid / 6, pg = tid - pr * 6;
    const bool pactive = interior_x | (pg < 4);

    // ---- Zero-fill raw (NaN defense: band-0 ring slots 42-47 and tx=15's
    // px 32-47 are MFMA-read but never written). rbt needs no fill: h-blur
    // writes every slot/col the v-blur reads, every band, before the read.
    {
        _Float16* base = &raw[0][0];
        const int total = 4 * 48 * 48;
        for (int i = tid * 8; i < total; i += 256 * 8)
            *(f4t*)(base + i) = f4t{0.f, 0.f, 0.f, 0.f};
    }

    // ---- Constant Toeplitz G fragment: B[k=quad8+j][n=nn] = g[k-n] (0 outside)
    h8 gfrag;
    #pragma unroll
    for (int j = 0; j < 8; ++j) {
        const int kk = quad8 + j - nn;
        float val = 0.f;
        #pragma unroll
        for (int t2 = 0; t2 < 11; ++t2) val = (kk == t2) ? gw.g[t2] : val;
        gfrag[j] = (_Float16)val;
    }
    const f4t zero4 = {0.f, 0.f, 0.f, 0.f};
    const float C1 = 1e-4f, C2 = 9e-4f;

    float mse_local = 0.f, ssim_local = 0.f;

    // ---- Prefetch band 0's global data into registers
    f4t pf0, pf1, pf2, pf3;
    {
        const int h0 = S, nnew = min(S + 42, H) - h0;   // 42 (interior strips)
        if ((tid < nnew * 6) & pactive) {
            const int base = ((h0 + pr) << 9) + ox0 + 8 * pg;
            pf0 = *(const f4t*)(pb + base);
            pf1 = *(const f4t*)(pb + base + 4);
            pf2 = *(const f4t*)(tb + base);
            pf3 = *(const f4t*)(tb + base + 4);
        }
    }

    __syncthreads();   // zeros visible before h-blur reads

    #pragma unroll 1
    for (int band = 0; band < NBANDS; ++band) {
        const int out0 = S + band * BAND;
        const int h0   = (band == 0) ? S : (out0 + 10);   // first NEW raw row
        const int nnew = min(out0 + 42, H) - h0;           // 42 / 32 / 22 (last)

        // ---- Consume prefetched registers: fp16-packed prep -> raw
        if ((tid < nnew * 6) & pactive) {
            const int gy = h0 + pr;
            const h2t hp0 = __builtin_amdgcn_cvt_pkrtz(pf0[0], pf0[1]);
            const h2t hp1 = __builtin_amdgcn_cvt_pkrtz(pf0[2], pf0[3]);
            const h2t hp2 = __builtin_amdgcn_cvt_pkrtz(pf1[0], pf1[1]);
            const h2t hp3 = __builtin_amdgcn_cvt_pkrtz(pf1[2], pf1[3]);
            const h2t ht0 = __builtin_amdgcn_cvt_pkrtz(pf2[0], pf2[1]);
            const h2t ht1 = __builtin_amdgcn_cvt_pkrtz(pf2[2], pf2[3]);
            const h2t ht2 = __builtin_amdgcn_cvt_pkrtz(pf3[0], pf3[1]);
            const h2t ht3 = __builtin_amdgcn_cvt_pkrtz(pf3[2], pf3[3]);
            __align__(16) h2t sv[4], dv[4], ssv[4], ddv[4];
            sv[0] = hp0 + ht0; sv[1] = hp1 + ht1; sv[2] = hp2 + ht2; sv[3] = hp3 + ht3;
            dv[0] = hp0 - ht0; dv[1] = hp1 - ht1; dv[2] = hp2 - ht2; dv[3] = hp3 - ht3;
            ssv[0] = sv[0] * sv[0]; ssv[1] = sv[1] * sv[1];
            ssv[2] = sv[2] * sv[2]; ssv[3] = sv[3] * sv[3];
            ddv[0] = dv[0] * dv[0]; ddv[1] = dv[1] * dv[1];
            ddv[2] = dv[2] * dv[2]; ddv[3] = dv[3] * dv[3];

            // MSE over owned px (groups 0-3 = cols ox0..ox0+31), owned rows
            if ((pg < 4) & (gy < mse_end)) {
                const h2t macc = (ddv[0] + ddv[1]) + (ddv[2] + ddv[3]);
                mse_local += (float)macc[0] + (float)macc[1];
            }

            int u = gy - S;                       // [0, 138)
            u -= (u >= 96) ? 96 : ((u >= 48) ? 48 : 0);
            const int off = u * 48 + 8 * pg;
            *(f4t*)&raw[0][off] = *(const f4t*)sv;
            *(f4t*)&raw[1][off] = *(const f4t*)dv;
            *(f4t*)&raw[2][off] = *(const f4t*)ssv;
            *(f4t*)&raw[3][off] = *(const f4t*)ddv;
        }
        __syncthreads();   // raw ready (also: all waves past last band's v-blur)

        // ---- Prefetch band+1's global data (overlaps the MFMA phases below)
        if (band + 1 < NBANDS) {
            const int nout0 = S + (band + 1) * BAND;
            const int nh0   = nout0 + 10;
            const int nnnew = min(nout0 + 42, H) - nh0;
            if ((tid < nnnew * 6) & pactive) {
                const int base = ((nh0 + pr) << 9) + ox0 + 8 * pg;
                pf0 = *(const f4t*)(pb + base);
                pf1 = *(const f4t*)(pb + base + 4);
                pf2 = *(const f4t*)(tb + base);
                pf3 = *(const f4t*)(tb + base + 4);
            }
        }

        // ---- H-blur via MFMA: 24 tiles (3 rowtiles x 2 coltiles x 4 ch), wave-strided
        #pragma unroll 1
        for (int t5 = wave; t5 < 24; t5 += 4) {
            const int ch = t5 & 3, rem = t5 >> 2;
            const int j0 = (rem & 1) << 4, r0 = (rem >> 1) << 4;
            int u = band * BAND + r0 + nn;            // raw ring row, [0, 144)
            u -= (u >= 96) ? 96 : ((u >= 48) ? 48 : 0);
            const h8 a = *(const h8*)&raw[ch][u * 48 + j0 + quad8];
            const f4t dacc = __builtin_amdgcn_mfma_f32_16x16x32_f16(a, gfrag, zero4, 0, 0, 0);
            // D[row=quad*4+reg][col=nn]: out col = j0+nn, out slot = r0+quad*4+reg
            h2t* wp = (h2t*)&rbt[ch][(j0 + nn) * 48 + r0 + (quad << 2)];
            wp[0] = __builtin_amdgcn_cvt_pkrtz(dacc[0], dacc[1]);
            wp[1] = __builtin_amdgcn_cvt_pkrtz(dacc[2], dacc[3]);
        }
        __syncthreads();   // rbt ready

        // ---- V-blur via MFMA (transposed) + SSIM epilogue: 1 out-tile per wave
        {
            const int c0 = (wave & 1) << 4, r0v = (wave >> 1) << 4;
            f4t dv2[4];
            #pragma unroll
            for (int ch = 0; ch < 4; ++ch) {
                const h8 a = *(const h8*)&rbt[ch][(c0 + nn) * 48 + r0v + quad8];
                dv2[ch] = __builtin_amdgcn_mfma_f32_16x16x32_f16(a, gfrag, zero4, 0, 0, 0);
            }
            // D[row=quad*4+reg][col=nn]: out row = out0+r0v+nn, out px col = c0+quad*4+reg
            const int rowg = out0 + r0v + nn;
            if (rowg < OUT_HW) {
                #pragma unroll
                for (int reg = 0; reg < 4; ++reg) {
                    const int cl = c0 + (quad << 2) + reg;
                    if (cl < cols) {
                        const float A = dv2[0][reg], Bv = dv2[1][reg];
                        const float U = dv2[2][reg], V  = dv2[3][reg];
                        const float A2 = A * A, B2 = Bv * Bv;
                        const float mu12_2 = 0.5f * (A2 - B2);   // 2*mu1*mu2
                        const float musq   = 0.5f * (A2 + B2);   // mu1^2+mu2^2
                        const float sig12_2 = 0.5f * (U - V) - mu12_2;
                        const float sigsum  = 0.5f * (U + V) - musq;
                        const float num = (mu12_2 + C1) * (sig12_2 + C2);
                        const float den = (musq + C1) * (sigsum + C2) + 1e-6f;
                        ssim_local += num * __builtin_amdgcn_rcpf(den);
                    }
                }
            }
        }
        // Next band's prep writes raw only (disjoint from rbt); the post-prep
        // barrier orders raw writes vs next h-blur reads, and the post-h-blur
        // barrier orders this band's v-blur reads vs next h-blur's rbt writes.
    }

    // ---- Block reduction (256 threads = 4 waves)
    #pragma unroll
    for (int off = 32; off > 0; off >>= 1) {
        ssim_local += __shfl_down(ssim_local, off, 64);
        mse_local  += __shfl_down(mse_local,  off, 64);
    }
    if ((tid & 63) == 0) { red[wave] = ssim_local; red[4 + wave] = mse_local; }
    __syncthreads();
    if (tid == 0) {
        const float s = red[0] + red[1] + red[2] + red[3];
        const float m = red[4] + red[5] + red[6] + red[7];
        const double contrib = 0.6 * (double)m / N1 - 0.4 * (double)s / N2;
        const int bid = (b * NSTRIP + sy) * NTX + tx;
        ws_contrib[bid] = (float)contrib;
    }
}

__global__ __launch_bounds__(1024)
void finalize_kernel(const float* __restrict__ ws_contrib,
                     float* __restrict__ out)
{
    __shared__ double rs[1024];
    int tid = threadIdx.x;
    double s = 0.0;
    for (int i = tid; i < NBLOCKS; i += 1024)
        s += (double)ws_contrib[i];
    rs[tid] = s;
    __syncthreads();
    for (int off = 512; off > 0; off >>= 1) {
        if (tid < off) rs[tid] += rs[tid + off];
        __syncthreads();
    }
    if (tid == 0)
        out[0] = (float)(0.4 + rs[0]);
}

extern "C" void kernel_launch(void* const* d_in, const int* in_sizes, int n_in,
                              void* d_out, int out_size, void* d_ws, size_t ws_size,
                              hipStream_t stream)
{
    const float* pred = (const float*)d_in[0];
    const float* targ = (const float*)d_in[1];
    float* out = (float*)d_out;
    float* ws_contrib = (float*)d_ws;

    // Gaussian taps: computed host-side in double, normalized, passed by value.
    GaussW gw;
    double g[11], sum = 0.0;
    for (int i = 0; i < 11; ++i) { double x = i - 5.0; g[i] = exp(-x * x / 4.5); sum += g[i]; }
    for (int i = 0; i < 11; ++i) gw.g[i] = (float)(g[i] / sum);

    ssim_mfma_kernel<<<dim3(NTX, NSTRIP, BATCH), 256, 0, stream>>>(pred, targ, ws_contrib, gw);
    finalize_kernel<<<1, 1024, 0, stream>>>(ws_contrib, out);
}